// Round 1
// baseline (2183.057 us; speedup 1.0000x reference)
//
#include <hip/hip_runtime.h>

#define BB 64
#define TT 2048
#define INW 64
#define HH 256
#define CHUNK 32
#define NCHUNK (TT / CHUNK)
#define RBW 36   // 32 floats of r per q-chunk + 4 pad floats (bank skew)

typedef float v2f __attribute__((ext_vector_type(2)));

__device__ __forceinline__ v2f fma2(v2f a, v2f b, v2f c) {
#if __has_builtin(__builtin_elementwise_fma)
    return __builtin_elementwise_fma(a, b, c);   // -> v_pk_fma_f32
#else
    v2f r; r.x = __builtin_fmaf(a.x, b.x, c.x); r.y = __builtin_fmaf(a.y, b.y, c.y); return r;
#endif
}

__device__ __forceinline__ float fast_tanh(float x) {
    // tanh(x) = 1 - 2/(e^{2x}+1); saturates correctly at +/-inf
    float e = __expf(2.0f * x);
    return 1.0f - 2.0f / (e + 1.0f);
}

// Barrier with LDS-only drain: skips the compiler's vmcnt(0) flush so
// outstanding global stores / staged loads never sit on the barrier path.
__device__ __forceinline__ void lds_barrier() {
    asm volatile("s_waitcnt lgkmcnt(0)" ::: "memory");
    __builtin_amdgcn_s_barrier();
    asm volatile("" ::: "memory");
}

// One workgroup per batch, 512 threads.
// Thread (g = tid>>3, q = tid&7): owns output rows h = 4g..4g+3 and
// k-range [32q, 32q+32) of W_rec (j-range [8q,8q+8) of W_in) in registers.
// Per step: 8x ds_read_b128 of r (skewed layout, conflict-free multicast)
// + 2x of I -> 80 v_pk_fma -> shfl_xor butterfly over q -> all lanes hold
// the full drive, update u redundantly -> q==0 stores u and writes r to the
// OTHER r-buffer. Single lgkm-only barrier per step.
// I is staged in 32-step chunks (double-buffered LDS), loaded a full chunk
// ahead, so no global-load latency is on the per-step path.
__global__ __launch_bounds__(512, 2)
void rnn_scan(const float* __restrict__ x0,
              const float* __restrict__ I,
              const float* __restrict__ W_in,
              const float* __restrict__ W_rec,
              const float* __restrict__ bias,
              float* __restrict__ u_out)
{
    __shared__ __align__(16) float rb[2][8 * RBW];          // 2.3 KB, skewed
    __shared__ __align__(16) float ibuf[2][CHUNK][INW];     // 16 KB

    const int b   = blockIdx.x;
    const int tid = threadIdx.x;
    const int q   = tid & 7;
    const int g   = tid >> 3;
    const int h0  = g << 2;

    // ---- loop-invariant weights into registers (160 VGPRs) ----
    v2f wr[4][16], wi[4][4];
    #pragma unroll
    for (int m = 0; m < 4; ++m) {
        const float4* wp = (const float4*)(W_rec + (size_t)(h0 + m) * HH + q * 32);
        #pragma unroll
        for (int i = 0; i < 8; ++i) {
            float4 w = wp[i];
            wr[m][2*i]     = (v2f){w.x, w.y};
            wr[m][2*i + 1] = (v2f){w.z, w.w};
        }
        const float4* ip = (const float4*)(W_in + (size_t)(h0 + m) * INW + q * 8);
        #pragma unroll
        for (int i = 0; i < 2; ++i) {
            float4 w = ip[i];
            wi[m][2*i]     = (v2f){w.x, w.y};
            wi[m][2*i + 1] = (v2f){w.z, w.w};
        }
    }

    // ---- state: u and bias held redundantly in ALL q-lanes of a g-group ----
    float u0, u1, u2, u3, bv0, bv1, bv2, bv3;
    {
        float4 xv = *(const float4*)(x0 + (size_t)b * HH + h0);
        float4 bb = *(const float4*)(bias + h0);
        u0 = xv.x; u1 = xv.y; u2 = xv.z; u3 = xv.w;
        bv0 = bb.x; bv1 = bb.y; bv2 = bb.z; bv3 = bb.w;
    }

    // r[h] lives at rb[p][RBW*(h>>5) + (h&31)]  (skewed: chunk stride 36)
    const int wslot = RBW * (g >> 3) + 4 * (g & 7);   // writer float offset (16B aligned)
    if (q == 0) {
        float4 r0 = { fast_tanh(u0), fast_tanh(u1), fast_tanh(u2), fast_tanh(u3) };
        *(float4*)&rb[0][wslot] = r0;
    }
    // stage chunk 0 of I
    {
        float4 iv = ((const float4*)(I + (size_t)b * TT * INW))[tid];
        ((float4*)&ibuf[0][0][0])[tid] = iv;
    }
    __syncthreads();

    float4 nxt = {0.f, 0.f, 0.f, 0.f};

    for (int t = 0; t < TT; ++t) {
        const int p    = t & 1;
        const int tin  = t & (CHUNK - 1);
        const int cpar = (t >> 5) & 1;

        // issue next-chunk load a full chunk (~32 steps) ahead of its use
        if (tin == 0) {
            const int ch1 = (t >> 5) + 1;
            if (ch1 < NCHUNK)
                nxt = ((const float4*)(I + ((size_t)b * TT + (size_t)ch1 * CHUNK) * INW))[tid];
        }

        // ---- partial dot: rows 4g..4g+3, k in [32q, 32q+32) ----
        const float4* rp = (const float4*)&rb[p][RBW * q];          // skew -> 8 distinct bank groups
        const float4* ip = (const float4*)&ibuf[cpar][tin][8 * q];  // 2-way multicast (free)

        v2f a0[4] = {{0.f,0.f},{0.f,0.f},{0.f,0.f},{0.f,0.f}};
        v2f a1[4] = {{0.f,0.f},{0.f,0.f},{0.f,0.f},{0.f,0.f}};
        #pragma unroll
        for (int i = 0; i < 8; ++i) {
            float4 r4 = rp[i];
            v2f r01 = (v2f){r4.x, r4.y}, r23 = (v2f){r4.z, r4.w};
            #pragma unroll
            for (int m = 0; m < 4; ++m) {
                a0[m] = fma2(wr[m][2*i],     r01, a0[m]);
                a1[m] = fma2(wr[m][2*i + 1], r23, a1[m]);
            }
        }
        #pragma unroll
        for (int i = 0; i < 2; ++i) {
            float4 r4 = ip[i];
            v2f r01 = (v2f){r4.x, r4.y}, r23 = (v2f){r4.z, r4.w};
            #pragma unroll
            for (int m = 0; m < 4; ++m) {
                a0[m] = fma2(wi[m][2*i],     r01, a0[m]);
                a1[m] = fma2(wi[m][2*i + 1], r23, a1[m]);
            }
        }
        v2f s0 = a0[0] + a1[0], s1 = a0[1] + a1[1];
        v2f s2 = a0[2] + a1[2], s3 = a0[3] + a1[3];
        float d0 = s0.x + s0.y, d1 = s1.x + s1.y;
        float d2 = s2.x + s2.y, d3 = s3.x + s3.y;

        // ---- butterfly over q (lane bits 0..2) -> every lane gets the total ----
        #pragma unroll
        for (int mask = 1; mask <= 4; mask <<= 1) {
            d0 += __shfl_xor(d0, mask, 64);
            d1 += __shfl_xor(d1, mask, 64);
            d2 += __shfl_xor(d2, mask, 64);
            d3 += __shfl_xor(d3, mask, 64);
        }

        // ---- state update, redundant in all q-lanes (same issue cost) ----
        u0 = 0.8f * u0 + 0.2f * (d0 + bv0);
        u1 = 0.8f * u1 + 0.2f * (d1 + bv1);
        u2 = 0.8f * u2 + 0.2f * (d2 + bv2);
        u3 = 0.8f * u3 + 0.2f * (d3 + bv3);
        float r0 = fast_tanh(u0), r1 = fast_tanh(u1);
        float r2 = fast_tanh(u2), r3 = fast_tanh(u3);

        if (q == 0) {
            float4 uv = {u0, u1, u2, u3};
            *(float4*)(u_out + ((size_t)b * TT + t) * HH + h0) = uv;
            float4 rv = {r0, r1, r2, r3};
            *(float4*)&rb[p ^ 1][wslot] = rv;
        }

        // write staged chunk to the idle buffer near the end of this chunk;
        // vmcnt wait here is ~30 steps after issue -> fully hidden
        if (tin == CHUNK - 2) {
            const int ch1 = (t >> 5) + 1;
            if (ch1 < NCHUNK)
                ((float4*)&ibuf[cpar ^ 1][0][0])[tid] = nxt;
        }

        lds_barrier();   // r[p^1] + (occasionally) ibuf visible for t+1
    }
}

// y[b,t,o] = sum_h u[b,t,h] * Wout[o,h] + bout[o]. One wave per (b,t) row.
__global__ __launch_bounds__(256)
void readout(const float* __restrict__ u,
             const float* __restrict__ Wout,
             const float* __restrict__ bout,
             float* __restrict__ y)
{
    const int wid  = threadIdx.x >> 6;
    const int lane = threadIdx.x & 63;
    const size_t row = (size_t)blockIdx.x * 4 + wid;   // < BB*TT

    float4 uv = ((const float4*)(u + row * HH))[lane];
    float4 w0 = ((const float4*)Wout)[lane];
    float4 w1 = ((const float4*)(Wout + HH))[lane];

    float acc0 = uv.x * w0.x + uv.y * w0.y + uv.z * w0.z + uv.w * w0.w;
    float acc1 = uv.x * w1.x + uv.y * w1.y + uv.z * w1.z + uv.w * w1.w;

    #pragma unroll
    for (int m = 32; m >= 1; m >>= 1) {
        acc0 += __shfl_xor(acc0, m, 64);
        acc1 += __shfl_xor(acc1, m, 64);
    }
    if (lane == 0) {
        y[row * 2 + 0] = acc0 + bout[0];
        y[row * 2 + 1] = acc1 + bout[1];
    }
}

extern "C" void kernel_launch(void* const* d_in, const int* in_sizes, int n_in,
                              void* d_out, int out_size, void* d_ws, size_t ws_size,
                              hipStream_t stream) {
    const float* x0    = (const float*)d_in[0];
    const float* I     = (const float*)d_in[1];
    const float* W_in  = (const float*)d_in[2];
    const float* W_rec = (const float*)d_in[3];
    const float* bias  = (const float*)d_in[4];
    const float* Wout  = (const float*)d_in[5];
    const float* bout  = (const float*)d_in[6];

    float* u_out = (float*)d_out;
    float* y_out = u_out + (size_t)BB * TT * HH;

    rnn_scan<<<BB, 512, 0, stream>>>(x0, I, W_in, W_rec, bias, u_out);
    readout<<<(BB * TT) / 4, 256, 0, stream>>>(u_out, Wout, bout, y_out);
}

// Round 2
// 1572.045 us; speedup vs baseline: 1.3887x; 1.3887x over previous
//
#include <hip/hip_runtime.h>

#define BB 64
#define TT 2048
#define INW 64
#define HH 256

typedef float v2f __attribute__((ext_vector_type(2)));

__device__ __forceinline__ v2f fma2(v2f a, v2f b, v2f c) {
#if __has_builtin(__builtin_elementwise_fma)
    return __builtin_elementwise_fma(a, b, c);   // -> v_pk_fma_f32
#else
    v2f r; r.x = __builtin_fmaf(a.x, b.x, c.x); r.y = __builtin_fmaf(a.y, b.y, c.y); return r;
#endif
}

__device__ __forceinline__ float fast_tanh(float x) {
    // tanh(x) = 1 - 2/(e^{2x}+1); saturates correctly at +/-inf
    float e = __expf(2.0f * x);
    return 1.0f - 2.0f / (e + 1.0f);
}

// Barrier with LDS-only drain: __syncthreads() emits s_waitcnt vmcnt(0)
// lgkmcnt(0) before s_barrier, which puts the u_out store-ack (~300-500 cyc)
// and the I-prefetch on the per-step critical path. All cross-thread data
// here is LDS, so lgkmcnt(0) alone is sufficient. sched_barrier(0) stops
// hipcc hoisting post-barrier LDS reads above it (skill rule #18).
__device__ __forceinline__ void lds_barrier() {
    asm volatile("s_waitcnt lgkmcnt(0)" ::: "memory");
    __builtin_amdgcn_s_barrier();
    __builtin_amdgcn_sched_barrier(0);
}

// One workgroup per batch, 512 threads.
// Thread decomposition: h2 = tid & 127, q = tid >> 7  (q in [0,4)).
// Thread (h2,q) owns W_rec rows {h2, h2+128}, k-range [64q, 64q+64), and
// W_in rows {h2, h2+128}, j-range [16q, 16q+16) -- all in registers (160 f32).
// Per step: partial dots -> part[q][h] -> barrier -> 256 threads combine,
// update u, write u_out, write r_buf -> barrier.
//
// __launch_bounds__(512, 1): grid is 64 blocks on 256 CUs, so >1 block/CU is
// unreachable -- min_waves=2 only halved the unified VGPR budget (256) and
// forced the 160 weight floats into AGPRs, adding v_accvgpr_read before every
// fma on the serial path (profiled: VGPR_Count=108, VALUBusy=14%). With 512
// unified VGPRs the weights stay in arch VGPRs.
__global__ __launch_bounds__(512, 1)
void rnn_scan(const float* __restrict__ x0,
              const float* __restrict__ I,
              const float* __restrict__ W_in,
              const float* __restrict__ W_rec,
              const float* __restrict__ bias,
              float* __restrict__ u_out)
{
    __shared__ __align__(16) float r_buf[HH];
    __shared__ __align__(16) float i_buf[INW];
    __shared__ float part[4][HH + 1];

    const int b   = blockIdx.x;
    const int tid = threadIdx.x;
    const int h2  = tid & 127;
    const int q   = tid >> 7;          // wave-uniform (waves 2w, 2w+1 share q)
    const int k0  = q * 64;
    const int j0  = q * 16;
    const int hA  = h2;
    const int hB  = h2 + 128;

    // ---- loop-invariant weights into registers ----
    v2f wrA[32], wrB[32], wiA[8], wiB[8];
    {
        const float4* wa = (const float4*)(W_rec + (size_t)hA * HH + k0);
        const float4* wb = (const float4*)(W_rec + (size_t)hB * HH + k0);
        #pragma unroll
        for (int i = 0; i < 16; ++i) {
            float4 a = wa[i], bq = wb[i];
            wrA[2*i]     = (v2f){a.x, a.y};  wrA[2*i + 1] = (v2f){a.z, a.w};
            wrB[2*i]     = (v2f){bq.x, bq.y}; wrB[2*i + 1] = (v2f){bq.z, bq.w};
        }
        const float4* ia = (const float4*)(W_in + (size_t)hA * INW + j0);
        const float4* ib = (const float4*)(W_in + (size_t)hB * INW + j0);
        #pragma unroll
        for (int i = 0; i < 4; ++i) {
            float4 a = ia[i], bq = ib[i];
            wiA[2*i]     = (v2f){a.x, a.y};  wiA[2*i + 1] = (v2f){a.z, a.w};
            wiB[2*i]     = (v2f){bq.x, bq.y}; wiB[2*i + 1] = (v2f){bq.z, bq.w};
        }
    }

    // ---- state init ----
    float u = 0.0f, bv = 0.0f;
    if (tid < HH) {
        u  = x0[(size_t)b * HH + tid];
        bv = bias[tid];
        r_buf[tid] = fast_tanh(u);
    }
    if (tid < INW) i_buf[tid] = I[((size_t)b * TT + 0) * INW + tid];
    __syncthreads();

    const float4* rb4 = (const float4*)&r_buf[k0];
    const float4* ib4 = (const float4*)&i_buf[j0];

    for (int t = 0; t < TT; ++t) {
        // prefetch next input row (independent, hides HBM/L3 latency)
        float i_next = 0.0f;
        if (tid < INW && (t + 1) < TT)
            i_next = I[((size_t)b * TT + (t + 1)) * INW + tid];

        v2f aA0 = {0.f,0.f}, aA1 = {0.f,0.f}, aB0 = {0.f,0.f}, aB1 = {0.f,0.f};
        #pragma unroll
        for (int i = 0; i < 16; ++i) {
            float4 r4 = rb4[i];                       // wave-uniform -> LDS broadcast
            v2f r01 = (v2f){r4.x, r4.y}, r23 = (v2f){r4.z, r4.w};
            aA0 = fma2(wrA[2*i],     r01, aA0);
            aA1 = fma2(wrA[2*i + 1], r23, aA1);
            aB0 = fma2(wrB[2*i],     r01, aB0);
            aB1 = fma2(wrB[2*i + 1], r23, aB1);
        }
        #pragma unroll
        for (int i = 0; i < 4; ++i) {
            float4 r4 = ib4[i];
            v2f r01 = (v2f){r4.x, r4.y}, r23 = (v2f){r4.z, r4.w};
            aA0 = fma2(wiA[2*i],     r01, aA0);
            aA1 = fma2(wiA[2*i + 1], r23, aA1);
            aB0 = fma2(wiB[2*i],     r01, aB0);
            aB1 = fma2(wiB[2*i + 1], r23, aB1);
        }
        v2f sA = aA0 + aA1, sB = aB0 + aB1;
        part[q][hA] = sA.x + sA.y;
        part[q][hB] = sB.x + sB.y;
        lds_barrier();                                 // partials visible; r/i reads done

        if (tid < HH) {
            float d = ((part[0][tid] + part[1][tid]) + (part[2][tid] + part[3][tid])) + bv;
            u = 0.8f * u + 0.2f * d;
            u_out[((size_t)b * TT + t) * HH + tid] = u;
            r_buf[tid] = fast_tanh(u);
        }
        if (tid < INW) i_buf[tid] = i_next;
        lds_barrier();                                 // new r/i visible for t+1
    }
}

// y[b,t,o] = sum_h u[b,t,h] * Wout[o,h] + bout[o]. One wave per (b,t) row.
__global__ __launch_bounds__(256)
void readout(const float* __restrict__ u,
             const float* __restrict__ Wout,
             const float* __restrict__ bout,
             float* __restrict__ y)
{
    const int wid  = threadIdx.x >> 6;
    const int lane = threadIdx.x & 63;
    const size_t row = (size_t)blockIdx.x * 4 + wid;   // < BB*TT

    float4 uv = ((const float4*)(u + row * HH))[lane];
    float4 w0 = ((const float4*)Wout)[lane];
    float4 w1 = ((const float4*)(Wout + HH))[lane];

    float acc0 = uv.x * w0.x + uv.y * w0.y + uv.z * w0.z + uv.w * w0.w;
    float acc1 = uv.x * w1.x + uv.y * w1.y + uv.z * w1.z + uv.w * w1.w;

    #pragma unroll
    for (int m = 32; m >= 1; m >>= 1) {
        acc0 += __shfl_xor(acc0, m, 64);
        acc1 += __shfl_xor(acc1, m, 64);
    }
    if (lane == 0) {
        y[row * 2 + 0] = acc0 + bout[0];
        y[row * 2 + 1] = acc1 + bout[1];
    }
}

extern "C" void kernel_launch(void* const* d_in, const int* in_sizes, int n_in,
                              void* d_out, int out_size, void* d_ws, size_t ws_size,
                              hipStream_t stream) {
    const float* x0    = (const float*)d_in[0];
    const float* I     = (const float*)d_in[1];
    const float* W_in  = (const float*)d_in[2];
    const float* W_rec = (const float*)d_in[3];
    const float* bias  = (const float*)d_in[4];
    const float* Wout  = (const float*)d_in[5];
    const float* bout  = (const float*)d_in[6];

    float* u_out = (float*)d_out;
    float* y_out = u_out + (size_t)BB * TT * HH;

    rnn_scan<<<BB, 512, 0, stream>>>(x0, I, W_in, W_rec, bias, u_out);
    readout<<<(BB * TT) / 4, 256, 0, stream>>>(u_out, Wout, bout, y_out);
}